// Round 9
// baseline (56.405 us; speedup 1.0000x reference)
//
#include <hip/hip_runtime.h>

typedef _Float16 f16x4 __attribute__((ext_vector_type(4)));
typedef __fp16 fp16x2 __attribute__((ext_vector_type(2)));   // cvt_pkrtz return type
typedef float f32x4 __attribute__((ext_vector_type(4)));

#define NBUCKETS 256
#define WT_OFF 1024          // weight-frag table offset in d_ws (bytes)

// ---- pre-kernel: zero buckets + build shared weight fragment ----
// Banded, translation-invariant: wf[kk][j] = w1[4g + j + 16kk - ln] (0 outside band).
// Serves as horizontal B-frag AND vertical A-frag for all tiles (validated R3/R5-R8).
__global__ void ssim_pre(const float* __restrict__ win, float* __restrict__ ws)
{
    int lane = threadIdx.x;            // 64 threads
#pragma unroll
    for (int i = 0; i < 4; ++i) ws[lane + 64 * i] = 0.f;   // zero buckets

    float w1[11];
#pragma unroll
    for (int i = 0; i < 11; ++i) {
        float s = 0.f;
#pragma unroll
        for (int j = 0; j < 11; ++j) s += win[i * 11 + j];
        w1[i] = s;                     // 1D gaussian (row sums; sum==1)
    }
    int g = lane >> 4, ln = lane & 15;
    _Float16* wt = (_Float16*)((char*)ws + WT_OFF) + lane * 8;
#pragma unroll
    for (int kk = 0; kk < 2; ++kk)
#pragma unroll
        for (int j = 0; j < 4; ++j) {
            int idx = 4 * g + j + 16 * kk - ln;
            wt[kk * 4 + j] = (_Float16)((idx >= 0 && idx < 11) ? w1[idx] : 0.f);
        }
}

__device__ __forceinline__ f16x4 cvt4(f32x4 a)
{
    union { fp16x2 h2[2]; f16x4 f; } u;
    u.h2[0] = __builtin_amdgcn_cvt_pkrtz(a[0], a[1]);
    u.h2[1] = __builtin_amdgcn_cvt_pkrtz(a[2], a[3]);
    return u.f;
}

__device__ __forceinline__ f16x4 cvt4f(float4 a)
{
    union { fp16x2 h2[2]; f16x4 f; } u;
    u.h2[0] = __builtin_amdgcn_cvt_pkrtz(a.x, a.y);
    u.h2[1] = __builtin_amdgcn_cvt_pkrtz(a.z, a.w);
    return u.f;
}

// ---- main: ONE wave per 16x32 output strip; no LDS, no barriers ----
// MFMA fragments loaded straight from global: lane (g,ln) reads rows ln+16*mt,
// cols 4g+16*kk -- each g-group's 4 lanes form a contiguous 64B segment.
// Clamped halo rows/cols only ever meet zero band-weights or discarded outputs.
__global__ __launch_bounds__(64, 4) void ssim_main(
    const float* __restrict__ raw, const float* __restrict__ dst,
    const float* __restrict__ ws_ro, float* __restrict__ buckets, int chunk)
{
    const int lane = threadIdx.x;
    const int g = lane >> 4;
    const int ln = lane & 15;

    // XCD-bijective swizzle (nwg % 8 == 0): XCD k gets a spatially-contiguous
    // run of strips -> halo re-reads stay in that XCD's L2.
    int wg = blockIdx.x;
    int sw = (wg & 7) * chunk + (wg >> 3);
    int sx = sw & 31;                  // x-strip   (16 wide)
    int sy = (sw >> 5) & 15;           // y-tile    (32 tall)
    int sz = sw >> 9;                  // image
    const int gx0 = sx * 16;
    const int gy0 = sy * 32;
    const float* rb = raw + (long)sz * (512 * 512);
    const float* db = dst + (long)sz * (512 * 512);

    const _Float16* wt = (const _Float16*)((const char*)ws_ro + WT_OFF) + lane * 8;
    f16x4 wf0 = *(const f16x4*)(wt);
    f16x4 wf1 = *(const f16x4*)(wt + 4);

    // ---- fragment loads straight from HBM/L2 (12 x dwordx4 per array pair) ----
    float4 Lr[6], Ld[6];
#pragma unroll
    for (int mt = 0; mt < 3; ++mt) {
        int row = gy0 + ln + 16 * mt; if (row > 511) row = 511;
        const float* pr = rb + (long)row * 512;
        const float* pd = db + (long)row * 512;
#pragma unroll
        for (int kk = 0; kk < 2; ++kk) {
            int col = gx0 + 4 * g + 16 * kk; if (col > 508) col = 508;
            Lr[mt * 2 + kk] = *(const float4*)(pr + col);
            Ld[mt * 2 + kk] = *(const float4*)(pd + col);
        }
    }

    // ---- horizontal conv -> register f16 frags (mu1, mu2, (r+d)^2, (r-d)^2) ----
    f16x4 hf[3][4];
#pragma unroll
    for (int mt = 0; mt < 3; ++mt) {
        f32x4 a0 = {0,0,0,0}, a1 = {0,0,0,0}, a2 = {0,0,0,0}, a3 = {0,0,0,0};
#pragma unroll
        for (int kk = 0; kk < 2; ++kk) {
            f16x4 rA = cvt4f(Lr[mt * 2 + kk]);
            f16x4 dA = cvt4f(Ld[mt * 2 + kk]);
            f16x4 wf = kk ? wf1 : wf0;
            f16x4 sA = rA + dA, qA = rA - dA;
            f16x4 ss = sA * sA, qq = qA * qA;
            a0 = __builtin_amdgcn_mfma_f32_16x16x16f16(rA, wf, a0, 0, 0, 0);
            a1 = __builtin_amdgcn_mfma_f32_16x16x16f16(dA, wf, a1, 0, 0, 0);
            a2 = __builtin_amdgcn_mfma_f32_16x16x16f16(ss, wf, a2, 0, 0, 0);
            a3 = __builtin_amdgcn_mfma_f32_16x16x16f16(qq, wf, a3, 0, 0, 0);
        }
        hf[mt][0] = cvt4(a0); hf[mt][1] = cvt4(a1);
        hf[mt][2] = cvt4(a2); hf[mt][3] = cvt4(a3);
    }

    // ---- vertical conv + SSIM epilogue (registers only) ----
    float lsum = 0.f;
    const int ox = gx0 + ln;
#define COMP_O(HA, HB, MTV)                                                   \
    {                                                                         \
        f32x4 z = {0, 0, 0, 0};                                               \
        f32x4 v0 = __builtin_amdgcn_mfma_f32_16x16x16f16(wf0, HA[0], z, 0, 0, 0); \
        f32x4 v1 = __builtin_amdgcn_mfma_f32_16x16x16f16(wf0, HA[1], z, 0, 0, 0); \
        f32x4 v2 = __builtin_amdgcn_mfma_f32_16x16x16f16(wf0, HA[2], z, 0, 0, 0); \
        f32x4 v3 = __builtin_amdgcn_mfma_f32_16x16x16f16(wf0, HA[3], z, 0, 0, 0); \
        v0 = __builtin_amdgcn_mfma_f32_16x16x16f16(wf1, HB[0], v0, 0, 0, 0);  \
        v1 = __builtin_amdgcn_mfma_f32_16x16x16f16(wf1, HB[1], v1, 0, 0, 0);  \
        v2 = __builtin_amdgcn_mfma_f32_16x16x16f16(wf1, HB[2], v2, 0, 0, 0);  \
        v3 = __builtin_amdgcn_mfma_f32_16x16x16f16(wf1, HB[3], v3, 0, 0, 0);  \
        int oy0 = gy0 + 16 * (MTV) + 4 * g;                                   \
        if (ox < 502) {                                                       \
            _Pragma("unroll")                                                 \
            for (int j = 0; j < 4; ++j) {                                     \
                if (oy0 + j < 502) {                                          \
                    float m1 = v0[j], m2 = v1[j], A = v2[j], B = v3[j];       \
                    float m1s = m1 * m1, m2s = m2 * m2, m12 = m1 * m2;        \
                    float num = (2.f * m12 + 6.5025f) *                       \
                                (0.5f * (A - B) - 2.f * m12 + 58.5225f);      \
                    float den = (m1s + m2s + 6.5025f) *                       \
                                (0.5f * (A + B) - m1s - m2s + 58.5225f);      \
                    lsum += __fdividef(num, den);                             \
                }                                                             \
            }                                                                 \
        }                                                                     \
    }
    COMP_O(hf[0], hf[1], 0)
    COMP_O(hf[1], hf[2], 1)
#undef COMP_O

    // wave reduce + scattered atomic
#pragma unroll
    for (int off = 32; off; off >>= 1) lsum += __shfl_down(lsum, off);
    if (lane == 0) atomicAdd(&buckets[wg & (NBUCKETS - 1)], lsum);
}

__global__ void ssim_finalize(const float* __restrict__ buckets,
                              float* __restrict__ out, float inv)
{
    int t = threadIdx.x;
    float s = 0.f;
    for (int i = t; i < NBUCKETS; i += 64) s += buckets[i];
#pragma unroll
    for (int off = 32; off; off >>= 1) s += __shfl_down(s, off);
    if (t == 0) out[0] = s * inv;
}

extern "C" void kernel_launch(void* const* d_in, const int* in_sizes, int n_in,
                              void* d_out, int out_size, void* d_ws, size_t ws_size,
                              hipStream_t stream) {
    const float* raw = (const float*)d_in[0];
    const float* dst = (const float*)d_in[1];
    const float* win = (const float*)d_in[2];
    float* out = (float*)d_out;
    float* ws = (float*)d_ws;

    int nimg = in_sizes[0] / (512 * 512);     // B*C = 48
    float inv = 1.0f / ((float)nimg * 502.f * 502.f);
    int nwg = 512 * nimg;                     // 32 x-strips * 16 y-tiles * nimg
    int chunk = nwg >> 3;                     // per-XCD contiguous run

    ssim_pre<<<1, 64, 0, stream>>>(win, ws);
    ssim_main<<<nwg, 64, 0, stream>>>(raw, dst, ws, ws, chunk);
    ssim_finalize<<<1, 64, 0, stream>>>(ws, out, inv);
}

// Round 10
// 39.265 us; speedup vs baseline: 1.4365x; 1.4365x over previous
//
#include <hip/hip_runtime.h>

typedef _Float16 f16x4 __attribute__((ext_vector_type(4)));
typedef __fp16 fp16x2 __attribute__((ext_vector_type(2)));   // cvt_pkrtz return type
typedef float f32x4 __attribute__((ext_vector_type(4)));

#define NBUCKETS 256
#define WT_OFF 1024          // weight-frag table offset in d_ws (bytes)
#define SSTR 80              // sr/sd row stride in halves
#define NLD 13               // staging float4 loads per thread (3200/256 = 12.5)

// ---- pre-kernel: zero buckets + build shared weight fragment ----
// Banded, translation-invariant: wf[kk][j] = w1[4g + j + 16kk - ln] (0 outside band).
// Serves as horizontal B-frag AND vertical A-frag for all tiles (validated R3/R5-R8).
__global__ void ssim_pre(const float* __restrict__ win, float* __restrict__ ws)
{
    int lane = threadIdx.x;            // 64 threads
#pragma unroll
    for (int i = 0; i < 4; ++i) ws[lane + 64 * i] = 0.f;   // zero buckets

    float w1[11];
#pragma unroll
    for (int i = 0; i < 11; ++i) {
        float s = 0.f;
#pragma unroll
        for (int j = 0; j < 11; ++j) s += win[i * 11 + j];
        w1[i] = s;                     // 1D gaussian (row sums; sum==1)
    }
    int g = lane >> 4, ln = lane & 15;
    _Float16* wt = (_Float16*)((char*)ws + WT_OFF) + lane * 8;
#pragma unroll
    for (int kk = 0; kk < 2; ++kk)
#pragma unroll
        for (int j = 0; j < 4; ++j) {
            int idx = 4 * g + j + 16 * kk - ln;
            wt[kk * 4 + j] = (_Float16)((idx >= 0 && idx < 11) ? w1[idx] : 0.f);
        }
}

__device__ __forceinline__ f16x4 cvt4(f32x4 a)
{
    union { fp16x2 h2[2]; f16x4 f; } u;
    u.h2[0] = __builtin_amdgcn_cvt_pkrtz(a[0], a[1]);
    u.h2[1] = __builtin_amdgcn_cvt_pkrtz(a[2], a[3]);
    return u.f;
}

// ---- main: 64x64 output region per block (2 x 64x32 tiles), 4 waves.
// Stage the UNION of both tiles' inputs (80x80) once -> ONE barrier per block;
// both tiles then compute back-to-back in registers (H frags via mfma D==B layout).
// Quantities: mu1, mu2, A=conv((r+d)^2), B=conv((r-d)^2).
__global__ __launch_bounds__(256, 4) void ssim_main(
    const float* __restrict__ raw, const float* __restrict__ dst,
    const float* __restrict__ ws_ro, float* __restrict__ buckets)
{
    __shared__ __align__(16) _Float16 sr[80 * SSTR];
    __shared__ __align__(16) _Float16 sd[80 * SSTR];

    const int tid = threadIdx.x;
    const int wv = tid >> 6;           // wave = 16-wide x-strip
    const int lane = tid & 63;
    const int g = lane >> 4;
    const int ln = lane & 15;
    const int nt = wv;

    const int gx0 = blockIdx.x * 64;
    const int ybase32 = blockIdx.y * 64;        // first input row of the region
    const long ioff = (long)blockIdx.z * (512 * 512);
    const float* rb = raw + ioff;
    const float* db = dst + ioff;

    const _Float16* wt = (const _Float16*)((const char*)ws_ro + WT_OFF) + lane * 8;
    f16x4 wf0 = *(const f16x4*)(wt);
    f16x4 wf1 = *(const f16x4*)(wt + 4);

    // ---- staging: 80 rows x {r,d} x 20 float4 chunks = 3200 tasks, clamped.
    // Phase 1: issue ALL loads (max MLP). Phase 2: recompute addrs (overlaps
    // the memory wait), pack f32->f16, write LDS. One barrier total.
    float4 fv[NLD];
#pragma unroll
    for (int k = 0; k < NLD; ++k) {
        int t = tid + 256 * k;
        if (k < NLD - 1 || t < 3200) {
            int chunk = t % 20;
            int sub = t / 20;          // 0..159
            int row = sub >> 1;        // 0..79
            int gy = ybase32 + row; if (gy > 511) gy = 511;
            int gxc = gx0 + 4 * chunk; if (gxc > 508) gxc = 508;
            const float* src = (sub & 1) ? db : rb;
            fv[k] = *reinterpret_cast<const float4*>(src + (long)gy * 512 + gxc);
        }
    }
#pragma unroll
    for (int k = 0; k < NLD; ++k) {
        int t = tid + 256 * k;
        if (k < NLD - 1 || t < 3200) {
            int chunk = t % 20;
            int sub = t / 20;
            int row = sub >> 1;
            _Float16* dstp = ((sub & 1) ? sd : sr) + row * SSTR + chunk * 4;
            union { fp16x2 h2[2]; uint2 u; } pk;
            pk.h2[0] = __builtin_amdgcn_cvt_pkrtz(fv[k].x, fv[k].y);
            pk.h2[1] = __builtin_amdgcn_cvt_pkrtz(fv[k].z, fv[k].w);
            *reinterpret_cast<uint2*>(dstp) = pk.u;
        }
    }
    __syncthreads();

    float lsum = 0.f;
    const int ox = gx0 + 16 * nt + ln;

#pragma unroll
    for (int it = 0; it < 2; ++it) {
        // ---- horizontal conv -> register f16 frags (4 quantities) ----
        f16x4 hf0[4], hf1[4], hf2[4];
#define COMP_H(HF, MT)                                                        \
        {                                                                     \
            f32x4 a0 = {0,0,0,0}, a1 = {0,0,0,0}, a2 = {0,0,0,0},             \
                  a3 = {0,0,0,0};                                             \
            const _Float16* pr = sr + (ln + 16 * (MT) + 32 * it) * SSTR + 16 * nt + 4 * g; \
            const _Float16* pd = sd + (ln + 16 * (MT) + 32 * it) * SSTR + 16 * nt + 4 * g; \
            _Pragma("unroll")                                                 \
            for (int kk = 0; kk < 2; ++kk) {                                  \
                f16x4 rA = *(const f16x4*)(pr + 16 * kk);                     \
                f16x4 dA = *(const f16x4*)(pd + 16 * kk);                     \
                f16x4 wf = kk ? wf1 : wf0;                                    \
                f16x4 sA = rA + dA, qA = rA - dA;                             \
                f16x4 ss = sA * sA, qq = qA * qA;                             \
                a0 = __builtin_amdgcn_mfma_f32_16x16x16f16(rA, wf, a0, 0, 0, 0); \
                a1 = __builtin_amdgcn_mfma_f32_16x16x16f16(dA, wf, a1, 0, 0, 0); \
                a2 = __builtin_amdgcn_mfma_f32_16x16x16f16(ss, wf, a2, 0, 0, 0); \
                a3 = __builtin_amdgcn_mfma_f32_16x16x16f16(qq, wf, a3, 0, 0, 0); \
            }                                                                 \
            HF[0] = cvt4(a0); HF[1] = cvt4(a1);                               \
            HF[2] = cvt4(a2); HF[3] = cvt4(a3);                               \
        }
        COMP_H(hf0, 0)
        COMP_H(hf1, 1)
        COMP_H(hf2, 2)
#undef COMP_H

        // ---- vertical conv + SSIM epilogue (registers only) ----
#define COMP_O(HA, HB, MTV)                                                   \
        {                                                                     \
            f32x4 z = {0, 0, 0, 0};                                           \
            f32x4 v0 = __builtin_amdgcn_mfma_f32_16x16x16f16(wf0, HA[0], z, 0, 0, 0); \
            f32x4 v1 = __builtin_amdgcn_mfma_f32_16x16x16f16(wf0, HA[1], z, 0, 0, 0); \
            f32x4 v2 = __builtin_amdgcn_mfma_f32_16x16x16f16(wf0, HA[2], z, 0, 0, 0); \
            f32x4 v3 = __builtin_amdgcn_mfma_f32_16x16x16f16(wf0, HA[3], z, 0, 0, 0); \
            v0 = __builtin_amdgcn_mfma_f32_16x16x16f16(wf1, HB[0], v0, 0, 0, 0); \
            v1 = __builtin_amdgcn_mfma_f32_16x16x16f16(wf1, HB[1], v1, 0, 0, 0); \
            v2 = __builtin_amdgcn_mfma_f32_16x16x16f16(wf1, HB[2], v2, 0, 0, 0); \
            v3 = __builtin_amdgcn_mfma_f32_16x16x16f16(wf1, HB[3], v3, 0, 0, 0); \
            int oy0 = ybase32 + 32 * it + 16 * (MTV) + 4 * g;                 \
            if (ox < 502) {                                                   \
                _Pragma("unroll")                                             \
                for (int j = 0; j < 4; ++j) {                                 \
                    if (oy0 + j < 502) {                                      \
                        float m1 = v0[j], m2 = v1[j], A = v2[j], B = v3[j];   \
                        float m1s = m1 * m1, m2s = m2 * m2, m12 = m1 * m2;    \
                        float num = (2.f * m12 + 6.5025f) *                   \
                                    (0.5f * (A - B) - 2.f * m12 + 58.5225f);  \
                        float den = (m1s + m2s + 6.5025f) *                   \
                                    (0.5f * (A + B) - m1s - m2s + 58.5225f);  \
                        lsum += __fdividef(num, den);                         \
                    }                                                         \
                }                                                             \
            }                                                                 \
        }
        COMP_O(hf0, hf1, 0)
        COMP_O(hf1, hf2, 1)
#undef COMP_O
    }

    // per-wave reduce + scattered atomic (no extra barrier)
#pragma unroll
    for (int off = 32; off; off >>= 1) lsum += __shfl_down(lsum, off);
    if (lane == 0) {
        int bucket = ((blockIdx.x + (blockIdx.y << 3) + blockIdx.z * 67) * 4 + wv) & (NBUCKETS - 1);
        atomicAdd(&buckets[bucket], lsum);
    }
}

__global__ void ssim_finalize(const float* __restrict__ buckets,
                              float* __restrict__ out, float inv)
{
    int t = threadIdx.x;
    float s = 0.f;
    for (int i = t; i < NBUCKETS; i += 64) s += buckets[i];
#pragma unroll
    for (int off = 32; off; off >>= 1) s += __shfl_down(s, off);
    if (t == 0) out[0] = s * inv;
}

extern "C" void kernel_launch(void* const* d_in, const int* in_sizes, int n_in,
                              void* d_out, int out_size, void* d_ws, size_t ws_size,
                              hipStream_t stream) {
    const float* raw = (const float*)d_in[0];
    const float* dst = (const float*)d_in[1];
    const float* win = (const float*)d_in[2];
    float* out = (float*)d_out;
    float* ws = (float*)d_ws;

    int nimg = in_sizes[0] / (512 * 512);     // B*C = 48
    float inv = 1.0f / ((float)nimg * 502.f * 502.f);

    ssim_pre<<<1, 64, 0, stream>>>(win, ws);
    dim3 grid(8, 8, nimg);                    // 64-wide x-tile, 64-tall y-region, image
    ssim_main<<<grid, 256, 0, stream>>>(raw, dst, ws, ws);
    ssim_finalize<<<1, 64, 0, stream>>>(ws, out, inv);
}